// Round 10
// baseline (353.014 us; speedup 1.0000x reference)
//
#include <hip/hip_runtime.h>
#include <hip/hip_bf16.h>

#define BB   131072
#define CC   16
#define DIN  256
#define DH   1024
#define DOUT 256
#define TM   128   // tokens per tile
#define NHB  32    // hidden blocks of 32
#define NB   512   // bucketing blocks (BB/NB = 256 tokens each)

typedef __attribute__((ext_vector_type(8))) short bf16x8;
typedef __attribute__((ext_vector_type(4))) short short4v;
typedef __attribute__((ext_vector_type(4))) float f32x4;

__device__ inline unsigned short f2b(float f) {
  union { float f; unsigned u; } v; v.f = f;
  unsigned u = v.u;
  return (unsigned short)((u + 0x7fffu + ((u >> 16) & 1u)) >> 16);  // RNE
}

__device__ inline void gload_lds16(const void* g, void* l) {
  __builtin_amdgcn_global_load_lds(
      (const __attribute__((address_space(1))) void*)g,
      (__attribute__((address_space(3))) void*)l, 16, 0, 0);
}

#define MFMA16(a, b, c) __builtin_amdgcn_mfma_f32_16x16x32_bf16((a), (b), (c), 0, 0, 0)

// ---------------- bucketing (contention-free counting sort) ----------------
__global__ void hist_k(const int* __restrict__ cat, int* __restrict__ blockhist) {
  __shared__ int h[CC];
  const int tid = threadIdx.x;
  if (tid < CC) h[tid] = 0;
  __syncthreads();
  const int i = blockIdx.x * 256 + tid;
  atomicAdd(&h[cat[i]], 1);
  __syncthreads();
  if (tid < CC) blockhist[blockIdx.x * CC + tid] = h[tid];
}

__global__ void offsets2_k(const int* __restrict__ blockhist,
                           int* __restrict__ counts, int* __restrict__ padoff,
                           int* __restrict__ base) {
  __shared__ int part[CC][64];
  __shared__ int pref[CC][64];
  __shared__ int scnt[CC];
  __shared__ int spad[CC + 1];
  const int tid = threadIdx.x;       // 1024 threads
  const int c = tid >> 6;
  const int g = tid & 63;
  int h[8];
  int s = 0;
#pragma unroll
  for (int i = 0; i < 8; i++) {
    h[i] = blockhist[(g * 8 + i) * CC + c];
    s += h[i];
  }
  part[c][g] = s;
  __syncthreads();
  if (g == 0) {
    int r = 0;
    for (int j = 0; j < 64; j++) { pref[c][j] = r; r += part[c][j]; }
    scnt[c] = r;
  }
  __syncthreads();
  if (tid == 0) {
    int acc = 0;
    for (int c2 = 0; c2 < CC; c2++) {
      spad[c2] = acc;
      padoff[c2] = acc;
      counts[c2] = scnt[c2];
      acc += ((scnt[c2] + TM - 1) / TM) * TM;
    }
    spad[CC] = acc;
    padoff[CC] = acc;
  }
  __syncthreads();
  int run = spad[c] + pref[c][g];
#pragma unroll
  for (int i = 0; i < 8; i++) {
    base[(g * 8 + i) * CC + c] = run;
    run += h[i];
  }
}

__global__ void scatter2_k(const int* __restrict__ cat, const int* __restrict__ base,
                           int* __restrict__ idx) {
  __shared__ int cur[CC];
  const int tid = threadIdx.x;
  if (tid < CC) cur[tid] = base[blockIdx.x * CC + tid];
  __syncthreads();
  const int i = blockIdx.x * 256 + tid;
  const int c = cat[i];
  const int pos = atomicAdd(&cur[c], 1);
  idx[pos] = i;
}

// -------- weight conversion: f32 -> bf16 in MFMA A-fragment order --------
// A-frag map (verified r1-r9): 16(row)x32(k) tile, lane = (row&15)+16*((k&31)>>3),
// byte j = (k&7)*2. Tiles stored [tile][lane][16B] = 1024 B.
// W1: per category [hb=32][nt=2][ks=8][lane][16B]  (16 KB per hb of 32 n)
__global__ void conv_w1_k(const float* __restrict__ W1, short* __restrict__ w1b) {
  int t = blockIdx.x * blockDim.x + threadIdx.x;   // 524288
  int n  = t & 1023;
  int j8 = (t >> 10) & 31;   // k-chunk of 8
  int c  = t >> 15;
  const float* src = W1 + (size_t)c * DIN * DH;
  bf16x8 o;
#pragma unroll
  for (int i = 0; i < 8; i++)
    o[i] = (short)f2b(src[(size_t)(j8 * 8 + i) * DH + n]);
  char* dst = (char*)w1b + (size_t)c * 524288
            + (n >> 5) * 16384 + ((n >> 4) & 1) * 8192 + (j8 >> 2) * 1024
            + ((n & 15) + 16 * (j8 & 3)) * 16;
  *(bf16x8*)dst = o;
}

// W2: per category [kb=32][nt=16][lane][16B]  (16 KB per k-block of 32)
__global__ void conv_w2_k(const float* __restrict__ W2, short* __restrict__ w2b) {
  int t = blockIdx.x * blockDim.x + threadIdx.x;   // 524288
  int n  = t & 255;
  int j8 = (t >> 8) & 127;   // k-chunk of 8 (k = hidden)
  int c  = t >> 15;
  const float* src = W2 + (size_t)c * DH * DOUT;
  bf16x8 o;
#pragma unroll
  for (int i = 0; i < 8; i++)
    o[i] = (short)f2b(src[(size_t)(j8 * 8 + i) * DOUT + n]);
  char* dst = (char*)w2b + (size_t)c * 524288
            + (j8 >> 2) * 16384 + (n >> 4) * 1024
            + ((n & 15) + 16 * (j8 & 3)) * 16;
  *(bf16x8*)dst = o;
}

// ---------------- fused routed MLP ----------------
// 256 thr = 4 waves. Each wave owns 2 token-tiles (32 tokens) and computes ALL
// hidden n and ALL 256 outputs for them. The L1->L2 handoff is wave-private:
// D-frag -> 4 ds_write_b64 into a private 2KB hs slab -> 2 ds_read_b128 B-frags
// (same-wave LDS ordering; NO barrier). Only barrier: weight-dbuf publish, 1/hb.
// LDS: w1 dbuf 2x16K @0 | w2 dbuf 2x16K @32K | hs 4x2K @64K | toks | b1s | b2s
#define W2OFF  32768
#define HSOFF  65536
#define TKOFF  73728
#define B1OFF  74240
#define B2OFF  78336
#define SMSZ   79360

__launch_bounds__(256, 2)
__global__ void mlp_k(const float* __restrict__ x,
                      const float* __restrict__ b1,
                      const float* __restrict__ b2,
                      const short* __restrict__ w1b,
                      const short* __restrict__ w2b,
                      const int* __restrict__ idx,
                      const int* __restrict__ padoff,
                      const int* __restrict__ counts,
                      float* __restrict__ out) {
  __shared__ __align__(16) char sm[SMSZ];

  const int bhw = blockIdx.x;
  const int wg = (bhw & 7) * 130 + (bhw >> 3);   // XCD-chunked swizzle, 1040 = 8*130
  const int p = wg * TM;
  const int total = padoff[CC];
  if (p >= total) return;
  int c = 0;
  while (padoff[c + 1] <= p) c++;
  const int cnt = counts[c];
  const int start = p - padoff[c];

  const int tid  = threadIdx.x;
  const int lane = tid & 63;
  const int w    = tid >> 6;   // 0..3: token-tile pair {2w, 2w+1}
  const int lrow = lane & 15;
  const int lgrp = lane >> 4;

  char*  hsb   = sm + HSOFF + w * 2048;          // wave-private slab
  int*   toksp = (int*)(sm + TKOFF);
  float* b1s   = (float*)(sm + B1OFF);
  float* b2s   = (float*)(sm + B2OFF);

  // ---- prologue: gather x, f32->bf16, B-frag order [tt=8][ks=8][lane][16B] in sm[0,64K) ----
  {
    const int r = tid >> 1;      // 0..127 token slot
    const int q = tid & 1;       // 128-float half
    const int pos = start + r;
    int tok = (pos < cnt) ? idx[p + r] : -1;
    if (q == 0) toksp[r] = tok;
    char* tb = sm + (r >> 4) * 8192 + (r & 15) * 16;
    if (tok >= 0) {
      const f32x4* src = (const f32x4*)(x + (size_t)tok * DIN);
#pragma unroll
      for (int k4 = 0; k4 < 4; k4++) {
        const int ks = q * 4 + k4;
#pragma unroll
        for (int m = 0; m < 4; m++) {
          f32x4 v0 = src[ks * 8 + m * 2];
          f32x4 v1 = src[ks * 8 + m * 2 + 1];
          bf16x8 o;
          o[0] = (short)f2b(v0[0]); o[1] = (short)f2b(v0[1]);
          o[2] = (short)f2b(v0[2]); o[3] = (short)f2b(v0[3]);
          o[4] = (short)f2b(v1[0]); o[5] = (short)f2b(v1[1]);
          o[6] = (short)f2b(v1[2]); o[7] = (short)f2b(v1[3]);
          *(bf16x8*)(tb + ks * 1024 + 16 * (16 * m)) = o;
        }
      }
    } else {
      bf16x8 z = {0, 0, 0, 0, 0, 0, 0, 0};
#pragma unroll
      for (int k4 = 0; k4 < 4; k4++) {
        const int ks = q * 4 + k4;
#pragma unroll
        for (int m = 0; m < 4; m++)
          *(bf16x8*)(tb + ks * 1024 + 16 * (16 * m)) = z;
      }
    }
    ((f32x4*)b1s)[tid] = ((const f32x4*)(b1 + (size_t)c * DH))[tid];
    if (tid < 64) ((f32x4*)b2s)[tid] = ((const f32x4*)(b2 + (size_t)c * DOUT))[tid];
  }
  __syncthreads();

  // ---- x fragments to registers: 2 token tiles ----
  bf16x8 xf[2][8];
#pragma unroll
  for (int ti = 0; ti < 2; ti++)
#pragma unroll
    for (int ks = 0; ks < 8; ks++)
      xf[ti][ks] = *(const bf16x8*)(sm + (2 * w + ti) * 8192 + ks * 1024 + lane * 16);
  __syncthreads();   // xs region free -> weight double buffers

  const char* w1g = (const char*)w1b + (size_t)c * 524288;
  const char* w2g = (const char*)w2b + (size_t)c * 524288;

  auto stage1 = [&](int i) {   // 16 KB linear, 4 vm ops/thread
    const char* src = w1g + (size_t)i * 16384;
    char* dst = sm + (i & 1) * 16384;
#pragma unroll
    for (int j = 0; j < 4; j++) {
      int chunk = (w * 4 + j) * 1024;
      gload_lds16(src + chunk + lane * 16, dst + chunk);
    }
  };
  auto stage2 = [&](int i) {   // 16 KB linear, 4 vm ops/thread
    const char* src = w2g + (size_t)i * 16384;
    char* dst = sm + W2OFF + (i & 1) * 16384;
#pragma unroll
    for (int j = 0; j < 4; j++) {
      int chunk = (w * 4 + j) * 1024;
      gload_lds16(src + chunk + lane * 16, dst + chunk);
    }
  };

  stage1(0);
  stage2(0);
  asm volatile("s_waitcnt vmcnt(0)" ::: "memory");
  __syncthreads();

  f32x4 acc2[2][16];   // [token tile][out tile] -> AGPRs
#pragma unroll
  for (int ti = 0; ti < 2; ti++)
#pragma unroll
    for (int ot = 0; ot < 16; ot++)
      acc2[ti][ot] = (f32x4){0.f, 0.f, 0.f, 0.f};

  // hs write base (D-frag -> B-frag position), constant per thread per (tt,nt):
  // byte = tt*1024 + (lrow + 16*(nt*2 + (lgrp>>1)))*16 + (lgrp&1)*8
  const int hw0 = (lrow + 16 * (lgrp >> 1)) * 16 + (lgrp & 1) * 8;   // nt=0
  const int hw1 = hw0 + 32 * 16;                                     // nt=1

  for (int i = 0; i < NHB; i++) {
    const char* w1c = sm + (i & 1) * 16384;
    const char* w2c = sm + W2OFF + (i & 1) * 16384;
    const bool notlast = (i < NHB - 1);

    if (notlast) { stage1(i + 1); stage2(i + 1); }   // 8 vm ops, drained at region end

    // ===== L1: 16 frag reads -> 32 MFMA (4 independent chains) =====
    f32x4 p00 = (f32x4){0.f, 0.f, 0.f, 0.f};
    f32x4 p10 = (f32x4){0.f, 0.f, 0.f, 0.f};
    f32x4 p01 = (f32x4){0.f, 0.f, 0.f, 0.f};
    f32x4 p11 = (f32x4){0.f, 0.f, 0.f, 0.f};
    __builtin_amdgcn_s_setprio(1);
#pragma unroll
    for (int ks = 0; ks < 8; ks++) {
      bf16x8 a0 = *(const bf16x8*)(w1c + ks * 1024 + lane * 16);
      bf16x8 a1 = *(const bf16x8*)(w1c + 8192 + ks * 1024 + lane * 16);
      p00 = MFMA16(a0, xf[0][ks], p00);
      p10 = MFMA16(a0, xf[1][ks], p10);
      p01 = MFMA16(a1, xf[0][ks], p01);
      p11 = MFMA16(a1, xf[1][ks], p11);
    }
    __builtin_amdgcn_s_setprio(0);

    // ===== bias+relu+pack -> wave-private hs (no barrier; same-wave LDS order) =====
    {
      f32x4 bv0 = *(const f32x4*)(b1s + i * 32 + lgrp * 4);
      f32x4 bv1 = *(const f32x4*)(b1s + i * 32 + 16 + lgrp * 4);
      short4v h;
#pragma unroll
      for (int jj = 0; jj < 4; jj++) h[jj] = (short)f2b(fmaxf(p00[jj] + bv0[jj], 0.0f));
      *(short4v*)(hsb + hw0) = h;
#pragma unroll
      for (int jj = 0; jj < 4; jj++) h[jj] = (short)f2b(fmaxf(p10[jj] + bv0[jj], 0.0f));
      *(short4v*)(hsb + 1024 + hw0) = h;
#pragma unroll
      for (int jj = 0; jj < 4; jj++) h[jj] = (short)f2b(fmaxf(p01[jj] + bv1[jj], 0.0f));
      *(short4v*)(hsb + hw1) = h;
#pragma unroll
      for (int jj = 0; jj < 4; jj++) h[jj] = (short)f2b(fmaxf(p11[jj] + bv1[jj], 0.0f));
      *(short4v*)(hsb + 1024 + hw1) = h;
    }

    // ===== L2: 2 hs reads + 16 frag reads -> 32 MFMA =====
    {
      bf16x8 hf0 = *(const bf16x8*)(hsb + lane * 16);
      bf16x8 hf1 = *(const bf16x8*)(hsb + 1024 + lane * 16);
      __builtin_amdgcn_s_setprio(1);
#pragma unroll
      for (int ot = 0; ot < 16; ot++) {
        bf16x8 a2 = *(const bf16x8*)(w2c + ot * 1024 + lane * 16);
        acc2[0][ot] = MFMA16(a2, hf0, acc2[0][ot]);
        acc2[1][ot] = MFMA16(a2, hf1, acc2[1][ot]);
      }
      __builtin_amdgcn_s_setprio(0);
    }

    // ===== publish weight dbuf(i+1): staged loads had a full region of cover =====
    if (notlast) {
      asm volatile("s_waitcnt vmcnt(0)" ::: "memory");
      __builtin_amdgcn_s_barrier();
    }
  }

  // ---- epilogue: + b2, vectorized scatter ----
#pragma unroll
  for (int ti = 0; ti < 2; ti++) {
    const int tok = toksp[(2 * w + ti) * 16 + lrow];
    if (tok >= 0) {
#pragma unroll
      for (int ot = 0; ot < 16; ot++) {
        const int n0 = ot * 16 + lgrp * 4;
        f32x4 bv = *(const f32x4*)(b2s + n0);
        f32x4 v = acc2[ti][ot] + bv;
        *(f32x4*)(out + (size_t)tok * DOUT + n0) = v;
      }
    }
  }
}

extern "C" void kernel_launch(void* const* d_in, const int* in_sizes, int n_in,
                              void* d_out, int out_size, void* d_ws, size_t ws_size,
                              hipStream_t stream) {
  (void)in_sizes; (void)n_in; (void)out_size; (void)ws_size;
  const float* x   = (const float*)d_in[0];
  const int*   cat = (const int*)d_in[1];
  const float* W1  = (const float*)d_in[2];
  const float* b1  = (const float*)d_in[3];
  const float* W2  = (const float*)d_in[4];
  const float* b2  = (const float*)d_in[5];
  float* out = (float*)d_out;

  char* ws = (char*)d_ws;
  int* counts    = (int*)(ws);
  int* padoff    = (int*)(ws + 128);
  int* blockhist = (int*)(ws + 4096);
  int* base      = (int*)(ws + 65536);
  int* idx       = (int*)(ws + 131072);
  short* w1b     = (short*)(ws + (1 << 20));
  short* w2b     = (short*)(ws + (1 << 20) + 8388608);

  hist_k<<<NB, 256, 0, stream>>>(cat, blockhist);
  offsets2_k<<<1, 1024, 0, stream>>>(blockhist, counts, padoff, base);
  scatter2_k<<<NB, 256, 0, stream>>>(cat, base, idx);
  conv_w1_k<<<2048, 256, 0, stream>>>(W1, w1b);
  conv_w2_k<<<2048, 256, 0, stream>>>(W2, w2b);

  const int ntiles = BB / TM + CC;   // 1040 = 8 * 130 (swizzle assumes this)
  mlp_k<<<ntiles, 256, 0, stream>>>(x, b1, b2, w1b, w2b, idx, padoff, counts, out);
}

// Round 11
// 247.797 us; speedup vs baseline: 1.4246x; 1.4246x over previous
//
#include <hip/hip_runtime.h>
#include <hip/hip_bf16.h>

#define BB   131072
#define CC   16
#define DIN  256
#define DH   1024
#define DOUT 256
#define TM   64    // tokens per tile
#define NHB  32    // hidden blocks of 32
#define NB   512   // bucketing blocks (BB/NB = 256 tokens each)

typedef __attribute__((ext_vector_type(8))) short bf16x8;
typedef __attribute__((ext_vector_type(4))) short short4v;
typedef __attribute__((ext_vector_type(4))) float f32x4;

__device__ inline unsigned short f2b(float f) {
  union { float f; unsigned u; } v; v.f = f;
  unsigned u = v.u;
  return (unsigned short)((u + 0x7fffu + ((u >> 16) & 1u)) >> 16);  // RNE
}

__device__ inline void gload_lds16(const void* g, void* l) {
  __builtin_amdgcn_global_load_lds(
      (const __attribute__((address_space(1))) void*)g,
      (__attribute__((address_space(3))) void*)l, 16, 0, 0);
}

#define MFMA16(a, b, c) __builtin_amdgcn_mfma_f32_16x16x32_bf16((a), (b), (c), 0, 0, 0)

// ---------------- bucketing (contention-free counting sort) ----------------
__global__ void hist_k(const int* __restrict__ cat, int* __restrict__ blockhist) {
  __shared__ int h[CC];
  const int tid = threadIdx.x;
  if (tid < CC) h[tid] = 0;
  __syncthreads();
  const int i = blockIdx.x * 256 + tid;
  atomicAdd(&h[cat[i]], 1);
  __syncthreads();
  if (tid < CC) blockhist[blockIdx.x * CC + tid] = h[tid];
}

__global__ void offsets2_k(const int* __restrict__ blockhist,
                           int* __restrict__ counts, int* __restrict__ padoff,
                           int* __restrict__ base) {
  __shared__ int part[CC][64];
  __shared__ int pref[CC][64];
  __shared__ int scnt[CC];
  __shared__ int spad[CC + 1];
  const int tid = threadIdx.x;       // 1024 threads
  const int c = tid >> 6;
  const int g = tid & 63;
  int h[8];
  int s = 0;
#pragma unroll
  for (int i = 0; i < 8; i++) {
    h[i] = blockhist[(g * 8 + i) * CC + c];
    s += h[i];
  }
  part[c][g] = s;
  __syncthreads();
  if (g == 0) {
    int r = 0;
    for (int j = 0; j < 64; j++) { pref[c][j] = r; r += part[c][j]; }
    scnt[c] = r;
  }
  __syncthreads();
  if (tid == 0) {
    int acc = 0;
    for (int c2 = 0; c2 < CC; c2++) {
      spad[c2] = acc;
      padoff[c2] = acc;
      counts[c2] = scnt[c2];
      acc += ((scnt[c2] + TM - 1) / TM) * TM;
    }
    spad[CC] = acc;
    padoff[CC] = acc;
  }
  __syncthreads();
  int run = spad[c] + pref[c][g];
#pragma unroll
  for (int i = 0; i < 8; i++) {
    base[(g * 8 + i) * CC + c] = run;
    run += h[i];
  }
}

__global__ void scatter2_k(const int* __restrict__ cat, const int* __restrict__ base,
                           int* __restrict__ idx) {
  __shared__ int cur[CC];
  const int tid = threadIdx.x;
  if (tid < CC) cur[tid] = base[blockIdx.x * CC + tid];
  __syncthreads();
  const int i = blockIdx.x * 256 + tid;
  const int c = cat[i];
  const int pos = atomicAdd(&cur[c], 1);
  idx[pos] = i;
}

// -------- weight conversion: f32 -> bf16 in MFMA A-fragment order --------
// A-frag map (verified r1-r10): 16(row)x32(k) tile, lane = (row&15)+16*((k&31)>>3),
// byte j = (k&7)*2. Tiles stored [tile][lane][16B] = 1024 B.
// W1: per category [hb=32][nt=2][ks=8][lane][16B]  (16 KB per hb of 32 n)
__global__ void conv_w1_k(const float* __restrict__ W1, short* __restrict__ w1b) {
  int t = blockIdx.x * blockDim.x + threadIdx.x;   // 524288
  int n  = t & 1023;
  int j8 = (t >> 10) & 31;   // k-chunk of 8
  int c  = t >> 15;
  const float* src = W1 + (size_t)c * DIN * DH;
  bf16x8 o;
#pragma unroll
  for (int i = 0; i < 8; i++)
    o[i] = (short)f2b(src[(size_t)(j8 * 8 + i) * DH + n]);
  char* dst = (char*)w1b + (size_t)c * 524288
            + (n >> 5) * 16384 + ((n >> 4) & 1) * 8192 + (j8 >> 2) * 1024
            + ((n & 15) + 16 * (j8 & 3)) * 16;
  *(bf16x8*)dst = o;
}

// W2: per category [kb=32][nt=16][lane][16B]  (16 KB per k-block of 32)
__global__ void conv_w2_k(const float* __restrict__ W2, short* __restrict__ w2b) {
  int t = blockIdx.x * blockDim.x + threadIdx.x;   // 524288
  int n  = t & 255;
  int j8 = (t >> 8) & 127;   // k-chunk of 8 (k = hidden)
  int c  = t >> 15;
  const float* src = W2 + (size_t)c * DH * DOUT;
  bf16x8 o;
#pragma unroll
  for (int i = 0; i < 8; i++)
    o[i] = (short)f2b(src[(size_t)(j8 * 8 + i) * DOUT + n]);
  char* dst = (char*)w2b + (size_t)c * 524288
            + (j8 >> 2) * 16384 + (n >> 4) * 1024
            + ((n & 15) + 16 * (j8 & 3)) * 16;
  *(bf16x8*)dst = o;
}

// ---------------- fused routed MLP ----------------
// 256 thr = 4 waves = wt(2: token-tile pair) x wh(2: n/out half). Tile = 64 tok.
// 2-way token reuse: each weight frag read feeds 2 MFMAs. 2 blocks/CU (74KB LDS,
// ~165 regs @ 2 waves/SIMD) -> independent blocks cover each other's stalls.
// Schedule per hb (r7-verified): regionA{stage(hb+1); L1; relu->hs; vmcnt(8)+bar}
//                                regionB{L2; vmcnt(4)+bar}
// LDS: w1 dbuf 2x16K @0 | w2 dbuf 2x16K @32K | hs 4K @64K | toks | b1s | b2s
#define W2OFF  32768
#define HSOFF  65536
#define TKOFF  69632
#define B1OFF  69888
#define B2OFF  73984
#define SMSZ   75008

__launch_bounds__(256, 2)
__global__ void mlp_k(const float* __restrict__ x,
                      const float* __restrict__ b1,
                      const float* __restrict__ b2,
                      const short* __restrict__ w1b,
                      const short* __restrict__ w2b,
                      const int* __restrict__ idx,
                      const int* __restrict__ padoff,
                      const int* __restrict__ counts,
                      float* __restrict__ out) {
  __shared__ __align__(16) char sm[SMSZ];

  const int bhw = blockIdx.x;
  const int wg = (bhw & 7) * 258 + (bhw >> 3);   // XCD-chunked swizzle, 2064 = 8*258
  const int p = wg * TM;
  const int total = padoff[CC];
  if (p >= total) return;
  int c = 0;
  while (padoff[c + 1] <= p) c++;
  const int cnt = counts[c];
  const int start = p - padoff[c];

  const int tid  = threadIdx.x;
  const int lane = tid & 63;
  const int w    = tid >> 6;   // 0..3
  const int wt   = w >> 1;     // 0..1: token-tile pair {2wt, 2wt+1}
  const int wh   = w & 1;      // L1: n-half of 32; L2: out-half of 256
  const int lrow = lane & 15;
  const int lgrp = lane >> 4;

  char*  hsb   = sm + HSOFF;
  int*   toksp = (int*)(sm + TKOFF);
  float* b1s   = (float*)(sm + B1OFF);
  float* b2s   = (float*)(sm + B2OFF);

  // ---- prologue: gather x, f32->bf16, B-frag order [tt=4][ks=8][lane][16B] ----
  {
    const int r = tid >> 2;      // 0..63 token slot
    const int q = tid & 3;       // 64-float quarter
    const int pos = start + r;
    int tok = (pos < cnt) ? idx[p + r] : -1;
    if (q == 0) toksp[r] = tok;
    char* tb = sm + (r >> 4) * 8192 + (r & 15) * 16;
    if (tok >= 0) {
      const f32x4* src = (const f32x4*)(x + (size_t)tok * DIN) + q * 16;
#pragma unroll
      for (int t = 0; t < 8; t++) {
        f32x4 v0 = src[2 * t];
        f32x4 v1 = src[2 * t + 1];
        bf16x8 o;
        o[0] = (short)f2b(v0[0]); o[1] = (short)f2b(v0[1]);
        o[2] = (short)f2b(v0[2]); o[3] = (short)f2b(v0[3]);
        o[4] = (short)f2b(v1[0]); o[5] = (short)f2b(v1[1]);
        o[6] = (short)f2b(v1[2]); o[7] = (short)f2b(v1[3]);
        *(bf16x8*)(tb + (2 * q + (t >> 2)) * 1024 + (t & 3) * 256) = o;
      }
    } else {
      bf16x8 z = {0, 0, 0, 0, 0, 0, 0, 0};
#pragma unroll
      for (int t = 0; t < 8; t++)
        *(bf16x8*)(tb + (2 * q + (t >> 2)) * 1024 + (t & 3) * 256) = z;
    }
    ((f32x4*)b1s)[tid] = ((const f32x4*)(b1 + (size_t)c * DH))[tid];
    if (tid < 64) ((f32x4*)b2s)[tid] = ((const f32x4*)(b2 + (size_t)c * DOUT))[tid];
  }
  __syncthreads();

  // ---- x fragments to registers: 2 token tiles ----
  bf16x8 xf[2][8];
#pragma unroll
  for (int ti = 0; ti < 2; ti++)
#pragma unroll
    for (int ks = 0; ks < 8; ks++)
      xf[ti][ks] = *(const bf16x8*)(sm + (2 * wt + ti) * 8192 + ks * 1024 + lane * 16);
  __syncthreads();   // xs region free -> weight double buffers

  const char* w1g = (const char*)w1b + (size_t)c * 524288;
  const char* w2g = (const char*)w2b + (size_t)c * 524288;

  auto stage1 = [&](int i) {   // 16 KB linear, 4 vm ops/thread
    const char* src = w1g + (size_t)i * 16384;
    char* dst = sm + (i & 1) * 16384;
#pragma unroll
    for (int j = 0; j < 4; j++) {
      int chunk = (w * 4 + j) * 1024;
      gload_lds16(src + chunk + lane * 16, dst + chunk);
    }
  };
  auto stage2 = [&](int i) {   // 16 KB linear, 4 vm ops/thread
    const char* src = w2g + (size_t)i * 16384;
    char* dst = sm + W2OFF + (i & 1) * 16384;
#pragma unroll
    for (int j = 0; j < 4; j++) {
      int chunk = (w * 4 + j) * 1024;
      gload_lds16(src + chunk + lane * 16, dst + chunk);
    }
  };

  stage1(0);
  stage2(0);
  asm volatile("s_waitcnt vmcnt(0)" ::: "memory");
  __syncthreads();

  f32x4 acc2[2][8];   // [token tile][out tile]
#pragma unroll
  for (int ti = 0; ti < 2; ti++)
#pragma unroll
    for (int ni = 0; ni < 8; ni++)
      acc2[ti][ni] = (f32x4){0.f, 0.f, 0.f, 0.f};

  // hs write position (D-frag -> B-frag order), constant per thread:
  const int hswr = (lrow + 16 * (wh * 2 + (lgrp >> 1))) * 16 + (lgrp & 1) * 8;

  for (int hb = 0; hb < NHB; hb++) {
    const char* w1c = sm + (hb & 1) * 16384 + wh * 8192;
    const char* w2c = sm + W2OFF + (hb & 1) * 16384;
    const bool notlast = (hb < NHB - 1);

    // ===== region A: issue stage(hb+1); L1 (8 reads -> 16 MFMA); relu -> hs =====
    if (notlast) { stage1(hb + 1); stage2(hb + 1); }   // 8 vm ops

    f32x4 p0 = (f32x4){0.f, 0.f, 0.f, 0.f};
    f32x4 p1 = (f32x4){0.f, 0.f, 0.f, 0.f};
    __builtin_amdgcn_s_setprio(1);
#pragma unroll
    for (int ks = 0; ks < 8; ks++) {
      bf16x8 a = *(const bf16x8*)(w1c + ks * 1024 + lane * 16);
      p0 = MFMA16(a, xf[0][ks], p0);
      p1 = MFMA16(a, xf[1][ks], p1);
    }
    __builtin_amdgcn_s_setprio(0);

    {
      f32x4 bv = *(const f32x4*)(b1s + hb * 32 + wh * 16 + lgrp * 4);
      short4v h0, h1;
#pragma unroll
      for (int jj = 0; jj < 4; jj++) {
        h0[jj] = (short)f2b(fmaxf(p0[jj] + bv[jj], 0.0f));
        h1[jj] = (short)f2b(fmaxf(p1[jj] + bv[jj], 0.0f));
      }
      *(short4v*)(hsb + (2 * wt) * 1024 + hswr)     = h0;
      *(short4v*)(hsb + (2 * wt + 1) * 1024 + hswr) = h1;
    }
    // w2[hb] landed (8 newest = stage(hb+1) may fly); hs published by barrier
    if (notlast)
      asm volatile("s_waitcnt vmcnt(8) lgkmcnt(0)" ::: "memory");
    else
      asm volatile("s_waitcnt vmcnt(0) lgkmcnt(0)" ::: "memory");
    __builtin_amdgcn_s_barrier();

    // ===== region B: L2 (10 reads -> 16 MFMA) =====
    {
      bf16x8 hf0 = *(const bf16x8*)(hsb + (2 * wt) * 1024 + lane * 16);
      bf16x8 hf1 = *(const bf16x8*)(hsb + (2 * wt + 1) * 1024 + lane * 16);
      __builtin_amdgcn_s_setprio(1);
#pragma unroll
      for (int ni = 0; ni < 8; ni++) {
        bf16x8 a2 = *(const bf16x8*)(w2c + (wh * 8 + ni) * 1024 + lane * 16);
        acc2[0][ni] = MFMA16(a2, hf0, acc2[0][ni]);
        acc2[1][ni] = MFMA16(a2, hf1, acc2[1][ni]);
      }
      __builtin_amdgcn_s_setprio(0);
    }
    // w1[hb+1] landed (4 newest = stage2(hb+1) may fly); hs reads drained
    if (notlast) {
      asm volatile("s_waitcnt vmcnt(4) lgkmcnt(0)" ::: "memory");
      __builtin_amdgcn_s_barrier();
    }
  }

  // ---- epilogue: + b2, vectorized scatter ----
#pragma unroll
  for (int ti = 0; ti < 2; ti++) {
    const int tok = toksp[(2 * wt + ti) * 16 + lrow];
    if (tok >= 0) {
#pragma unroll
      for (int ni = 0; ni < 8; ni++) {
        const int n0 = wh * 128 + ni * 16 + lgrp * 4;
        f32x4 bv = *(const f32x4*)(b2s + n0);
        f32x4 v = acc2[ti][ni] + bv;
        *(f32x4*)(out + (size_t)tok * DOUT + n0) = v;
      }
    }
  }
}

extern "C" void kernel_launch(void* const* d_in, const int* in_sizes, int n_in,
                              void* d_out, int out_size, void* d_ws, size_t ws_size,
                              hipStream_t stream) {
  (void)in_sizes; (void)n_in; (void)out_size; (void)ws_size;
  const float* x   = (const float*)d_in[0];
  const int*   cat = (const int*)d_in[1];
  const float* W1  = (const float*)d_in[2];
  const float* b1  = (const float*)d_in[3];
  const float* W2  = (const float*)d_in[4];
  const float* b2  = (const float*)d_in[5];
  float* out = (float*)d_out;

  char* ws = (char*)d_ws;
  int* counts    = (int*)(ws);
  int* padoff    = (int*)(ws + 128);
  int* blockhist = (int*)(ws + 4096);
  int* base      = (int*)(ws + 65536);
  int* idx       = (int*)(ws + 131072);
  short* w1b     = (short*)(ws + (1 << 20));
  short* w2b     = (short*)(ws + (1 << 20) + 8388608);

  hist_k<<<NB, 256, 0, stream>>>(cat, blockhist);
  offsets2_k<<<1, 1024, 0, stream>>>(blockhist, counts, padoff, base);
  scatter2_k<<<NB, 256, 0, stream>>>(cat, base, idx);
  conv_w1_k<<<2048, 256, 0, stream>>>(W1, w1b);
  conv_w2_k<<<2048, 256, 0, stream>>>(W2, w2b);

  const int ntiles = BB / TM + CC;   // 2064 = 8 * 258 (swizzle assumes this)
  mlp_k<<<ntiles, 256, 0, stream>>>(x, b1, b2, w1b, w2b, idx, padoff, counts, out);
}

// Round 12
// 218.255 us; speedup vs baseline: 1.6174x; 1.1354x over previous
//
#include <hip/hip_runtime.h>
#include <hip/hip_bf16.h>

#define BB   131072
#define CC   16
#define DIN  256
#define DH   1024
#define DOUT 256
#define TM   64    // tokens per tile
#define NHB  32    // hidden blocks of 32
#define NB   512   // bucketing blocks (BB/NB = 256 tokens each)

typedef __attribute__((ext_vector_type(8))) short bf16x8;
typedef __attribute__((ext_vector_type(4))) short short4v;
typedef __attribute__((ext_vector_type(4))) float f32x4;

__device__ inline unsigned short f2b(float f) {
  union { float f; unsigned u; } v; v.f = f;
  unsigned u = v.u;
  return (unsigned short)((u + 0x7fffu + ((u >> 16) & 1u)) >> 16);  // RNE
}

__device__ inline void gload_lds16(const void* g, void* l) {
  __builtin_amdgcn_global_load_lds(
      (const __attribute__((address_space(1))) void*)g,
      (__attribute__((address_space(3))) void*)l, 16, 0, 0);
}

#define MFMA16(a, b, c) __builtin_amdgcn_mfma_f32_16x16x32_bf16((a), (b), (c), 0, 0, 0)

// ---------------- bucketing (contention-free counting sort) ----------------
__global__ void hist_k(const int* __restrict__ cat, int* __restrict__ blockhist) {
  __shared__ int h[CC];
  const int tid = threadIdx.x;
  if (tid < CC) h[tid] = 0;
  __syncthreads();
  const int i = blockIdx.x * 256 + tid;
  atomicAdd(&h[cat[i]], 1);
  __syncthreads();
  if (tid < CC) blockhist[blockIdx.x * CC + tid] = h[tid];
}

__global__ void offsets2_k(const int* __restrict__ blockhist,
                           int* __restrict__ counts, int* __restrict__ padoff,
                           int* __restrict__ base) {
  __shared__ int part[CC][64];
  __shared__ int pref[CC][64];
  __shared__ int scnt[CC];
  __shared__ int spad[CC + 1];
  const int tid = threadIdx.x;       // 1024 threads
  const int c = tid >> 6;
  const int g = tid & 63;
  int h[8];
  int s = 0;
#pragma unroll
  for (int i = 0; i < 8; i++) {
    h[i] = blockhist[(g * 8 + i) * CC + c];
    s += h[i];
  }
  part[c][g] = s;
  __syncthreads();
  if (g == 0) {
    int r = 0;
    for (int j = 0; j < 64; j++) { pref[c][j] = r; r += part[c][j]; }
    scnt[c] = r;
  }
  __syncthreads();
  if (tid == 0) {
    int acc = 0;
    for (int c2 = 0; c2 < CC; c2++) {
      spad[c2] = acc;
      padoff[c2] = acc;
      counts[c2] = scnt[c2];
      acc += ((scnt[c2] + TM - 1) / TM) * TM;
    }
    spad[CC] = acc;
    padoff[CC] = acc;
  }
  __syncthreads();
  int run = spad[c] + pref[c][g];
#pragma unroll
  for (int i = 0; i < 8; i++) {
    base[(g * 8 + i) * CC + c] = run;
    run += h[i];
  }
}

__global__ void scatter2_k(const int* __restrict__ cat, const int* __restrict__ base,
                           int* __restrict__ idx) {
  __shared__ int cur[CC];
  const int tid = threadIdx.x;
  if (tid < CC) cur[tid] = base[blockIdx.x * CC + tid];
  __syncthreads();
  const int i = blockIdx.x * 256 + tid;
  const int c = cat[i];
  const int pos = atomicAdd(&cur[c], 1);
  idx[pos] = i;
}

// -------- weight conversion: f32 -> bf16 in MFMA A-fragment order --------
// A-frag map (verified r1-r11): 16(row)x32(k) tile, lane = (row&15)+16*((k&31)>>3),
// byte j = (k&7)*2. Tiles stored [tile][lane][16B] = 1024 B.
// W1: per category [hb=32][nt=2][ks=8][lane][16B]  (16 KB per hb of 32 n)
__global__ void conv_w1_k(const float* __restrict__ W1, short* __restrict__ w1b) {
  int t = blockIdx.x * blockDim.x + threadIdx.x;   // 524288
  int n  = t & 1023;
  int j8 = (t >> 10) & 31;   // k-chunk of 8
  int c  = t >> 15;
  const float* src = W1 + (size_t)c * DIN * DH;
  bf16x8 o;
#pragma unroll
  for (int i = 0; i < 8; i++)
    o[i] = (short)f2b(src[(size_t)(j8 * 8 + i) * DH + n]);
  char* dst = (char*)w1b + (size_t)c * 524288
            + (n >> 5) * 16384 + ((n >> 4) & 1) * 8192 + (j8 >> 2) * 1024
            + ((n & 15) + 16 * (j8 & 3)) * 16;
  *(bf16x8*)dst = o;
}

// W2: per category [kb=32][nt=16][lane][16B]  (16 KB per k-block of 32)
__global__ void conv_w2_k(const float* __restrict__ W2, short* __restrict__ w2b) {
  int t = blockIdx.x * blockDim.x + threadIdx.x;   // 524288
  int n  = t & 255;
  int j8 = (t >> 8) & 127;   // k-chunk of 8 (k = hidden)
  int c  = t >> 15;
  const float* src = W2 + (size_t)c * DH * DOUT;
  bf16x8 o;
#pragma unroll
  for (int i = 0; i < 8; i++)
    o[i] = (short)f2b(src[(size_t)(j8 * 8 + i) * DOUT + n]);
  char* dst = (char*)w2b + (size_t)c * 524288
            + (j8 >> 2) * 16384 + (n >> 4) * 1024
            + ((n & 15) + 16 * (j8 & 3)) * 16;
  *(bf16x8*)dst = o;
}

// ---------------- fused routed MLP ----------------
// 256 thr = 4 waves = wt(2: token-tile pair) x wh(2). Tile = 64 tokens.
// SINGLE-buffered w1/w2 (42.2 KB LDS -> 3 blocks/CU = 12 waves/CU for TLP).
// Hazard-safe retiming with the 2 barriers/hb:
//   A(i): issue stage2(i) [safe: B(i-1) barrier drained w2 reads]; L1; pack hs;
//         vmcnt(0)+lgkm(0)+bar  [w2(i) landed, hs published]
//   B(i): issue stage1(i+1) [safe: A(i) barrier drained w1 reads]; L2;
//         vmcnt(0)+lgkm(0)+bar  [w1(i+1) landed]
// LDS: w1 16K @0 | w2 16K @16K | hs 4K @32K | toks | b1s | b2s  (42240 B)
#define W2OFF  16384
#define HSOFF  32768
#define TKOFF  36864
#define B1OFF  37120
#define B2OFF  41216
#define SMSZ   42240

__launch_bounds__(256, 3)
__global__ void mlp_k(const float* __restrict__ x,
                      const float* __restrict__ b1,
                      const float* __restrict__ b2,
                      const short* __restrict__ w1b,
                      const short* __restrict__ w2b,
                      const int* __restrict__ idx,
                      const int* __restrict__ padoff,
                      const int* __restrict__ counts,
                      float* __restrict__ out) {
  __shared__ __align__(16) char sm[SMSZ];

  const int bhw = blockIdx.x;
  const int wg = (bhw & 7) * 258 + (bhw >> 3);   // XCD-chunked swizzle, 2064 = 8*258
  const int p = wg * TM;
  const int total = padoff[CC];
  if (p >= total) return;
  int c = 0;
  while (padoff[c + 1] <= p) c++;
  const int cnt = counts[c];
  const int start = p - padoff[c];

  const int tid  = threadIdx.x;
  const int lane = tid & 63;
  const int w    = tid >> 6;   // 0..3
  const int wt   = w >> 1;     // 0..1: token-tile pair {2wt, 2wt+1}
  const int wh   = w & 1;      // L1: n-half of 32; L2: out-half of 256
  const int lrow = lane & 15;
  const int lgrp = lane >> 4;

  char*  hsb   = sm + HSOFF;
  int*   toksp = (int*)(sm + TKOFF);
  float* b1s   = (float*)(sm + B1OFF);
  float* b2s   = (float*)(sm + B2OFF);

  // ---- prologue: gather x, f32->bf16, B-frag order [tt=4][ks=8][lane][16B] ----
  // xs occupies sm[0,32K) = w1s+w2s region (freed before staging starts)
  {
    const int r = tid >> 2;      // 0..63 token slot
    const int q = tid & 3;       // 64-float quarter
    const int pos = start + r;
    int tok = (pos < cnt) ? idx[p + r] : -1;
    if (q == 0) toksp[r] = tok;
    char* tb = sm + (r >> 4) * 8192 + (r & 15) * 16;
    if (tok >= 0) {
      const f32x4* src = (const f32x4*)(x + (size_t)tok * DIN) + q * 16;
#pragma unroll
      for (int t = 0; t < 8; t++) {
        f32x4 v0 = src[2 * t];
        f32x4 v1 = src[2 * t + 1];
        bf16x8 o;
        o[0] = (short)f2b(v0[0]); o[1] = (short)f2b(v0[1]);
        o[2] = (short)f2b(v0[2]); o[3] = (short)f2b(v0[3]);
        o[4] = (short)f2b(v1[0]); o[5] = (short)f2b(v1[1]);
        o[6] = (short)f2b(v1[2]); o[7] = (short)f2b(v1[3]);
        *(bf16x8*)(tb + (2 * q + (t >> 2)) * 1024 + (t & 3) * 256) = o;
      }
    } else {
      bf16x8 z = {0, 0, 0, 0, 0, 0, 0, 0};
#pragma unroll
      for (int t = 0; t < 8; t++)
        *(bf16x8*)(tb + (2 * q + (t >> 2)) * 1024 + (t & 3) * 256) = z;
    }
    ((f32x4*)b1s)[tid] = ((const f32x4*)(b1 + (size_t)c * DH))[tid];
    if (tid < 64) ((f32x4*)b2s)[tid] = ((const f32x4*)(b2 + (size_t)c * DOUT))[tid];
  }
  __syncthreads();

  // ---- x fragments to registers: 2 token tiles ----
  bf16x8 xf[2][8];
#pragma unroll
  for (int ti = 0; ti < 2; ti++)
#pragma unroll
    for (int ks = 0; ks < 8; ks++)
      xf[ti][ks] = *(const bf16x8*)(sm + (2 * wt + ti) * 8192 + ks * 1024 + lane * 16);
  __syncthreads();   // xs region free -> weight buffers

  const char* w1g = (const char*)w1b + (size_t)c * 524288;
  const char* w2g = (const char*)w2b + (size_t)c * 524288;

  auto stage1 = [&](int i) {   // 16 KB linear, 4 vm ops/thread
    const char* src = w1g + (size_t)i * 16384;
#pragma unroll
    for (int j = 0; j < 4; j++) {
      int chunk = (w * 4 + j) * 1024;
      gload_lds16(src + chunk + lane * 16, sm + chunk);
    }
  };
  auto stage2 = [&](int i) {   // 16 KB linear, 4 vm ops/thread
    const char* src = w2g + (size_t)i * 16384;
#pragma unroll
    for (int j = 0; j < 4; j++) {
      int chunk = (w * 4 + j) * 1024;
      gload_lds16(src + chunk + lane * 16, sm + W2OFF + chunk);
    }
  };

  stage1(0);
  asm volatile("s_waitcnt vmcnt(0)" ::: "memory");
  __syncthreads();   // w1[0] ready

  f32x4 acc2[2][8];   // [token tile][out tile]
#pragma unroll
  for (int ti = 0; ti < 2; ti++)
#pragma unroll
    for (int ni = 0; ni < 8; ni++)
      acc2[ti][ni] = (f32x4){0.f, 0.f, 0.f, 0.f};

  // hs write position (D-frag -> B-frag order), constant per thread:
  const int hswr = (lrow + 16 * (wh * 2 + (lgrp >> 1))) * 16 + (lgrp & 1) * 8;
  const char* w1c = sm + wh * 8192;
  const char* w2c = sm + W2OFF;

  for (int hb = 0; hb < NHB; hb++) {
    const bool notlast = (hb < NHB - 1);

    // ===== region A: issue stage2(hb); L1 (8 reads -> 16 MFMA); relu -> hs =====
    stage2(hb);   // 4 vm ops; safe: B(hb-1) end-barrier drained all w2 reads

    f32x4 p0 = (f32x4){0.f, 0.f, 0.f, 0.f};
    f32x4 p1 = (f32x4){0.f, 0.f, 0.f, 0.f};
    __builtin_amdgcn_s_setprio(1);
#pragma unroll
    for (int ks = 0; ks < 8; ks++) {
      bf16x8 a = *(const bf16x8*)(w1c + ks * 1024 + lane * 16);
      p0 = MFMA16(a, xf[0][ks], p0);
      p1 = MFMA16(a, xf[1][ks], p1);
    }
    __builtin_amdgcn_s_setprio(0);

    {
      f32x4 bv = *(const f32x4*)(b1s + hb * 32 + wh * 16 + lgrp * 4);
      short4v h0, h1;
#pragma unroll
      for (int jj = 0; jj < 4; jj++) {
        h0[jj] = (short)f2b(fmaxf(p0[jj] + bv[jj], 0.0f));
        h1[jj] = (short)f2b(fmaxf(p1[jj] + bv[jj], 0.0f));
      }
      *(short4v*)(hsb + (2 * wt) * 1024 + hswr)     = h0;
      *(short4v*)(hsb + (2 * wt + 1) * 1024 + hswr) = h1;
    }
    // w2[hb] landed (full L1 region of cover); hs published by barrier
    asm volatile("s_waitcnt vmcnt(0) lgkmcnt(0)" ::: "memory");
    __builtin_amdgcn_s_barrier();

    // ===== region B: issue stage1(hb+1); L2 (10 reads -> 16 MFMA) =====
    if (notlast) stage1(hb + 1);   // safe: A(hb) end-barrier drained all w1 reads

    {
      bf16x8 hf0 = *(const bf16x8*)(hsb + (2 * wt) * 1024 + lane * 16);
      bf16x8 hf1 = *(const bf16x8*)(hsb + (2 * wt + 1) * 1024 + lane * 16);
      __builtin_amdgcn_s_setprio(1);
#pragma unroll
      for (int ni = 0; ni < 8; ni++) {
        bf16x8 a2 = *(const bf16x8*)(w2c + (wh * 8 + ni) * 1024 + lane * 16);
        acc2[0][ni] = MFMA16(a2, hf0, acc2[0][ni]);
        acc2[1][ni] = MFMA16(a2, hf1, acc2[1][ni]);
      }
      __builtin_amdgcn_s_setprio(0);
    }
    // w1[hb+1] landed (full L2 region of cover); hs reads drained before rewrite
    if (notlast) {
      asm volatile("s_waitcnt vmcnt(0) lgkmcnt(0)" ::: "memory");
      __builtin_amdgcn_s_barrier();
    }
  }

  // ---- epilogue: + b2, vectorized scatter ----
#pragma unroll
  for (int ti = 0; ti < 2; ti++) {
    const int tok = toksp[(2 * wt + ti) * 16 + lrow];
    if (tok >= 0) {
#pragma unroll
      for (int ni = 0; ni < 8; ni++) {
        const int n0 = wh * 128 + ni * 16 + lgrp * 4;
        f32x4 bv = *(const f32x4*)(b2s + n0);
        f32x4 v = acc2[ti][ni] + bv;
        *(f32x4*)(out + (size_t)tok * DOUT + n0) = v;
      }
    }
  }
}

extern "C" void kernel_launch(void* const* d_in, const int* in_sizes, int n_in,
                              void* d_out, int out_size, void* d_ws, size_t ws_size,
                              hipStream_t stream) {
  (void)in_sizes; (void)n_in; (void)out_size; (void)ws_size;
  const float* x   = (const float*)d_in[0];
  const int*   cat = (const int*)d_in[1];
  const float* W1  = (const float*)d_in[2];
  const float* b1  = (const float*)d_in[3];
  const float* W2  = (const float*)d_in[4];
  const float* b2  = (const float*)d_in[5];
  float* out = (float*)d_out;

  char* ws = (char*)d_ws;
  int* counts    = (int*)(ws);
  int* padoff    = (int*)(ws + 128);
  int* blockhist = (int*)(ws + 4096);
  int* base      = (int*)(ws + 65536);
  int* idx       = (int*)(ws + 131072);
  short* w1b     = (short*)(ws + (1 << 20));
  short* w2b     = (short*)(ws + (1 << 20) + 8388608);

  hist_k<<<NB, 256, 0, stream>>>(cat, blockhist);
  offsets2_k<<<1, 1024, 0, stream>>>(blockhist, counts, padoff, base);
  scatter2_k<<<NB, 256, 0, stream>>>(cat, base, idx);
  conv_w1_k<<<2048, 256, 0, stream>>>(W1, w1b);
  conv_w2_k<<<2048, 256, 0, stream>>>(W2, w2b);

  const int ntiles = BB / TM + CC;   // 2064 = 8 * 258 (swizzle assumes this)
  mlp_k<<<ntiles, 256, 0, stream>>>(x, b1, b2, w1b, w2b, idx, padoff, counts, out);
}